// Round 11
// baseline (13043.533 us; speedup 1.0000x reference)
//
#include <hip/hip_runtime.h>
#include <hip/hip_bf16.h>

typedef __bf16 bf16x8 __attribute__((ext_vector_type(8)));
typedef __bf16 bf16x4 __attribute__((ext_vector_type(4)));
typedef float  f32x4  __attribute__((ext_vector_type(4)));
typedef unsigned int u32x2 __attribute__((ext_vector_type(2)));
typedef unsigned int u32x4 __attribute__((ext_vector_type(4)));

#define NSTEP 2048
#define NB    32     // batch
#define DH    1024   // hidden = d_model = d_res
#define MTOT  (NSTEP * NB)   // 65536
#define NWORK 8      // worker WGs in rnn_scan
#define NFILL 240    // clock-pinning filler WGs (248 <= 256 CUs -> all resident)
#define FILLER_CAP 120000
#define TMAX  (4 * NSTEP)

__device__ __forceinline__ f32x4 mfma16(bf16x8 a, bf16x8 b, f32x4 c) {
    return __builtin_amdgcn_mfma_f32_16x16x32_bf16(a, b, c, 0, 0, 0);
}

__device__ __forceinline__ void load_lds16(const __bf16* g, void* l) {
    __builtin_amdgcn_global_load_lds(
        (const __attribute__((address_space(1))) void*)g,
        (__attribute__((address_space(3))) void*)l, 16, 0, 0);
}

__device__ __forceinline__ float tanh_fast(float x) {
    float e = exp2f(x * 2.8853900817779268f);
    return 1.0f - 2.0f * __builtin_amdgcn_rcpf(e + 1.0f);
}

// ---------------- prep: convert weights to bf16, sum biases, zero flags ----
__global__ __launch_bounds__(256) void prep_kernel(
    const float* __restrict__ Wih, const float* __restrict__ Whh,
    const float* __restrict__ Wout, const float* __restrict__ bih,
    const float* __restrict__ bhh,
    __bf16* __restrict__ Wih_b, __bf16* __restrict__ Whh_b,
    __bf16* __restrict__ Wout_b, float* __restrict__ bias,
    int* __restrict__ flags)
{
    const int i = blockIdx.x * 256 + threadIdx.x;   // 0..262143
    const size_t off = (size_t)i * 4;
    {
        float4 a = *(const float4*)(Wih + off);
        bf16x4 o = {(__bf16)a.x, (__bf16)a.y, (__bf16)a.z, (__bf16)a.w};
        *(bf16x4*)(Wih_b + off) = o;
    }
    {
        float4 a = *(const float4*)(Whh + off);
        bf16x4 o = {(__bf16)a.x, (__bf16)a.y, (__bf16)a.z, (__bf16)a.w};
        *(bf16x4*)(Whh_b + off) = o;
    }
    {
        float4 a = *(const float4*)(Wout + off);
        bf16x4 o = {(__bf16)a.x, (__bf16)a.y, (__bf16)a.z, (__bf16)a.w};
        *(bf16x4*)(Wout_b + off) = o;
    }
    if (i < DH) bias[i] = bih[i] + bhh[i];
    if (i < 64) {
        int z = 0;
        asm volatile("global_store_dword %0, %1, off sc0 sc1"
                     :: "v"(&flags[i]), "v"(z) : "memory");
    }
}

// ---------------- x fp32 -> bf16 -----------------------------------------
__global__ __launch_bounds__(256) void cvt_bf16_x(
    const float* __restrict__ in, __bf16* __restrict__ outb)
{
    const size_t i = ((size_t)blockIdx.x * 256 + threadIdx.x) * 8;
    float4 a = *(const float4*)(in + i);
    float4 b = *(const float4*)(in + i + 4);
    bf16x8 o = { (__bf16)a.x, (__bf16)a.y, (__bf16)a.z, (__bf16)a.w,
                 (__bf16)b.x, (__bf16)b.y, (__bf16)b.z, (__bf16)b.w };
    *(bf16x8*)(outb + i) = o;
}

// ---------------- bf16 GEMM, C = A(MxK) * B(NxK)^T (+bias), bf16 out ------
__global__ __launch_bounds__(256) void gemm_bt(
    const __bf16* __restrict__ A,
    const __bf16* __restrict__ B,
    const float*  __restrict__ bias,
    __bf16* __restrict__ C,
    int M, int N, int K)
{
    __shared__ __bf16 sA[128 * 64];
    __shared__ __bf16 sB[128 * 64];
    const int nTn = N >> 7;
    const int tm = (int)(blockIdx.x / nTn) << 7;
    const int tn = (int)(blockIdx.x % nTn) << 7;
    const int t = threadIdx.x;
    const int w = t >> 6, l = t & 63;
    const int wy = w & 1, wx = w >> 1;
    const int l16 = l & 15, lhi = l >> 4;
    const int rw = t >> 3;
    const int kc = (t & 7) << 3;

    const __bf16* ga = A + (size_t)(tm + rw) * K + kc;
    const __bf16* gb = B + (size_t)(tn + rw) * K + kc;
    char* lA = (char*)sA + (w * 8) * 128;
    char* lB = (char*)sB + (w * 8) * 128;

    f32x4 acc[4][4] = {};

    for (int k0 = 0; k0 < K; k0 += 64) {
#pragma unroll
        for (int i = 0; i < 4; ++i) {
            load_lds16(ga + (size_t)(i * 32) * K + k0, lA + i * 32 * 128);
            load_lds16(gb + (size_t)(i * 32) * K + k0, lB + i * 32 * 128);
        }
        asm volatile("s_waitcnt vmcnt(0)" ::: "memory");
        __syncthreads();
#pragma unroll
        for (int kk = 0; kk < 2; ++kk) {
            bf16x8 af[4], bfr[4];
#pragma unroll
            for (int i = 0; i < 4; ++i) {
                af[i]  = *(const bf16x8*)(sA + (wy * 64 + i * 16 + l16) * 64 + kk * 32 + lhi * 8);
                bfr[i] = *(const bf16x8*)(sB + (wx * 64 + i * 16 + l16) * 64 + kk * 32 + lhi * 8);
            }
#pragma unroll
            for (int i = 0; i < 4; ++i)
#pragma unroll
                for (int j = 0; j < 4; ++j)
                    acc[i][j] = mfma16(af[i], bfr[j], acc[i][j]);
        }
        __syncthreads();
    }
#pragma unroll
    for (int j = 0; j < 4; ++j) {
        const int col = tn + wx * 64 + j * 16 + l16;
        const float bv = bias ? bias[col] : 0.0f;
#pragma unroll
        for (int i = 0; i < 4; ++i) {
            __bf16* cp = C + (size_t)(tm + wy * 64 + i * 16 + lhi * 4) * N + col;
#pragma unroll
            for (int r = 0; r < 4; ++r)
                cp[(size_t)r * N] = (__bf16)(acc[i][j][r] + bv);
        }
    }
}

// ---------------- persistent RNN scan: 4-phase staggered pipeline ---------
// Batches split into 4 phases of 8 (independent chains). Sub-slot tau
// processes phase tau&3 at step tau>>2; phase p's h stored at tau is
// consumed at tau+4, with loads issued at tau+... (one sub-slot early) ->
// 3 sub-slots of visibility slack: poll is a counted wait, retries rare.
// 8 WGs x 8 waves; wave = 16 j x 8 b (MFMA cols 8-15 duplicate b, unstored);
// W-slice 16x1024 bf16 = 128 VGPR/wave. Per sub-slot: wait prefetched 16KB
// phase-slab (tag-retry if stale), ds_write XOR-swizzled, barrier, 32 MFMA,
// tanh, tagged store to hx slot + plain store to hs.
// vmcnt(2) at sub-slot start waits the 3 prefetch loads but leaves the 2
// store-acks in flight (loads issued before stores each body; in-order
// retirement). Store data/addr regs double-buffered across unroll x2 bodies
// with fake-use liveness extension: tau-2's stores provably retired at tau's
// vmcnt(2), so reuse is safe.
__device__ __forceinline__ void subslot(
    int tau, int gb, int t, int bl, int jc, bool wlane,
    unsigned wb0, unsigned wb1, unsigned rbase, unsigned rx,
    const bf16x8* wreg,
    const __bf16* __restrict__ pre,
    __bf16* __restrict__ hs,
    __bf16* __restrict__ hx,
    char (&slab)[2][16384],
    u32x4& pf0, u32x4& pf1, u32x2& pvn,
    u32x2& uv, __bf16*& px, __bf16*& ps)
{
    const int p_ = tau & 3;
    const int s_ = tau >> 2;
    const int b_ = p_ * 8 + bl;
    const int bi = tau & 1;
    f32x4 a0 = {0.f, 0.f, 0.f, 0.f}, a1 = a0, a2 = a0, a3 = a0;
    bf16x4 pv;

    if (s_ > 0) {
        asm volatile("s_waitcnt vmcnt(2)" ::: "memory");
        __builtin_amdgcn_sched_barrier(0);
        pv = __builtin_bit_cast(bf16x4, pvn);
        const unsigned rep = (unsigned)((((s_ - 1) >> 1) & 1) + 1) * 0x00010001u;
        const char* pb = (const char*)hx
            + ((size_t)((p_ << 1) + ((s_ - 1) & 1)) << 14) + (size_t)t * 32;
        for (;;) {
            unsigned bad = (pf0[0] ^ rep) | (pf0[1] ^ rep) | (pf0[2] ^ rep) | (pf0[3] ^ rep)
                         | (pf1[0] ^ rep) | (pf1[1] ^ rep) | (pf1[2] ^ rep) | (pf1[3] ^ rep);
            if (__all((bad & 0x00030003u) == 0u)) break;
            asm volatile("global_load_dwordx4 %0, %2, off sc0 sc1\n\t"
                         "global_load_dwordx4 %1, %2, off offset:16 sc0 sc1\n\t"
                         "s_waitcnt vmcnt(0)"
                         : "=v"(pf0), "=v"(pf1) : "v"(pb) : "memory");
            __builtin_amdgcn_sched_barrier(0);
        }
        *(u32x4*)(&slab[bi][wb0]) = pf0;
        *(u32x4*)(&slab[bi][wb1]) = pf1;
    } else {
        // prologue: direct pre load; vmcnt(0) also drains prologue stores
        asm volatile("global_load_dwordx2 %0, %1, off\n\t"
                     "s_waitcnt vmcnt(0)"
                     : "=v"(pvn)
                     : "v"(pre + ((size_t)s_ * NB + b_) * DH + jc) : "memory");
        __builtin_amdgcn_sched_barrier(0);
        pv = __builtin_bit_cast(bf16x4, pvn);
    }
    __syncthreads();   // ds_writes visible (incl. lgkmcnt drain -> pf regs free)

    // prefetch for tau+1 (loads BEFORE this body's stores -> vmcnt(2) works)
    {
        const int t1 = tau + 1;
        if (t1 < TMAX) {
            const int p1 = t1 & 3, s1 = t1 >> 2;
            if (s1 >= 1) {
                const char* nb = (const char*)hx
                    + ((size_t)((p1 << 1) + ((s1 - 1) & 1)) << 14) + (size_t)t * 32;
                asm volatile("global_load_dwordx4 %0, %2, off sc0 sc1\n\t"
                             "global_load_dwordx4 %1, %2, off offset:16 sc0 sc1"
                             : "=v"(pf0), "=v"(pf1) : "v"(nb) : "memory");
                asm volatile("global_load_dwordx2 %0, %1, off"
                             : "=v"(pvn)
                             : "v"(pre + ((size_t)s1 * NB + (p1 * 8 + bl)) * DH + jc)
                             : "memory");
            }
        }
    }

    if (s_ > 0) {
#pragma unroll
        for (int c = 0; c < 32; c += 4) {
            bf16x8 h0 = *(const bf16x8*)(&slab[bi][(rbase + (unsigned)(c + 0) * 64) ^ rx]);
            bf16x8 h1 = *(const bf16x8*)(&slab[bi][(rbase + (unsigned)(c + 1) * 64) ^ rx]);
            bf16x8 h2 = *(const bf16x8*)(&slab[bi][(rbase + (unsigned)(c + 2) * 64) ^ rx]);
            bf16x8 h3 = *(const bf16x8*)(&slab[bi][(rbase + (unsigned)(c + 3) * 64) ^ rx]);
            a0 = mfma16(wreg[c + 0], h0, a0);
            a1 = mfma16(wreg[c + 1], h1, a1);
            a2 = mfma16(wreg[c + 2], h2, a2);
            a3 = mfma16(wreg[c + 3], h3, a3);
        }
    }
    f32x4 as = (a0 + a1) + (a2 + a3);

    float h0 = tanh_fast(as[0] + (float)pv[0]);
    float h1 = tanh_fast(as[1] + (float)pv[1]);
    float h2 = tanh_fast(as[2] + (float)pv[2]);
    float h3 = tanh_fast(as[3] + (float)pv[3]);
    const unsigned tag = (unsigned)(((s_ >> 1) & 1) + 1);
    unsigned u0 = (unsigned)__builtin_bit_cast(unsigned short, (__bf16)h0);
    unsigned u1 = (unsigned)__builtin_bit_cast(unsigned short, (__bf16)h1);
    unsigned u2 = (unsigned)__builtin_bit_cast(unsigned short, (__bf16)h2);
    unsigned u3 = (unsigned)__builtin_bit_cast(unsigned short, (__bf16)h3);
    u0 = ((u0 + 2u) & 0xFFFCu) | tag;
    u1 = ((u1 + 2u) & 0xFFFCu) | tag;
    u2 = ((u2 + 2u) & 0xFFFCu) | tag;
    u3 = ((u3 + 2u) & 0xFFFCu) | tag;
    uv[0] = u0 | (u1 << 16);
    uv[1] = u2 | (u3 << 16);
    px = hx + ((size_t)((p_ << 1) + (s_ & 1)) << 13) + (size_t)bl * 1024 + jc;
    ps = hs + ((size_t)s_ * NB + b_) * DH + jc;
    if (wlane) {
        asm volatile("global_store_dwordx2 %0, %1, off sc0 sc1"
                     :: "v"(px), "v"(uv) : "memory");
        asm volatile("global_store_dwordx2 %0, %1, off"
                     :: "v"(ps), "v"(uv) : "memory");
    }
}

__global__ __launch_bounds__(512, 1) void rnn_scan(
    const __bf16* __restrict__ Whh,   // [1024][1024] bf16 (row j, col k)
    const __bf16* __restrict__ pre,   // [2048][32][1024] bf16
    __bf16* __restrict__ hs,          // [2048][32][1024] bf16 (plain, for GEMM)
    __bf16* __restrict__ hx,          // [4 phase][2 parity][8 b][1024 j] bf16
    int* __restrict__ flags)          // [0] = done flag
{
    const int gb = blockIdx.x;
    if (gb >= NWORK) {
        // ---- clock-pinning filler (poll every 64 iters) ----
        float a = (float)(threadIdx.x + gb) * 1.0e-6f + 1.0f;
        const float m = 1.000001f, d = 0.999999f;
        const int* dp = flags;
        for (int it = 0; it < FILLER_CAP; ++it) {
#pragma unroll
            for (int u = 0; u < 128; ++u) {
                a = __builtin_fmaf(a, m, 1.0e-12f);
                a = __builtin_fmaf(a, d, -1.0e-12f);
            }
            if ((it & 63) == 0) {
                int dn;
                asm volatile("global_load_dword %0, %1, off sc0 sc1\n\t"
                             "s_waitcnt vmcnt(0)"
                             : "=v"(dn) : "v"(dp) : "memory");
                if (dn != 0) break;
            }
        }
        asm volatile("" :: "v"(a));
        return;
    }

    __shared__ char slab[2][16384];    // double-buffered 16KB phase slab
    const int t = threadIdx.x;         // 0..511
    const int w = t >> 6;              // 0..7 (all waves same phase)
    const int l = t & 63;
    const int l16 = l & 15;
    const int lhi = l >> 4;
    const int bl = l16 & 7;            // batch-local 0..7 (cols 8-15 duplicate)
    const int j0 = gb * 128 + w * 16;  // wave's 16 output cols (W rows)
    const int jc = j0 + lhi * 4;       // 4 output cols this lane stores
    const bool wlane = (l16 < 8);

    // A-operand (W rows j0..j0+15): wreg[c] covers k in [c*32, c*32+32)
    bf16x8 wreg[32];
    {
        const __bf16* wb = Whh + (size_t)(j0 + l16) * DH + lhi * 8;
#pragma unroll
        for (int c = 0; c < 32; ++c)
            wreg[c] = *(const bf16x8*)(wb + c * 32);
    }

    // LDS staging geometry: thread t stages slab bytes [t*32, t*32+32);
    // row (batch) = t>>6; XOR-swizzle spreads rows across 16B slots.
    const unsigned wrow = (unsigned)(t >> 6) & 7u;
    const unsigned wb0 = ((unsigned)t * 32) ^ (wrow << 4);
    const unsigned wb1 = ((unsigned)t * 32 + 16) ^ (wrow << 4);
    const unsigned rbase = (unsigned)bl * 2048 + (unsigned)lhi * 16;
    const unsigned rx = (unsigned)bl << 4;

    u32x4 pf0 = {}, pf1 = {};
    u32x2 pvn = {};
    u32x2 uvA = {}, uvB = {};
    __bf16 *pxA = hx, *psA = hs, *pxB = hx, *psB = hs;

    for (int tau = 0; tau < TMAX; tau += 2) {
        subslot(tau, gb, t, bl, jc, wlane, wb0, wb1, rbase, rx, wreg,
                pre, hs, hx, slab, pf0, pf1, pvn, uvA, pxA, psA);
        asm volatile("" :: "v"(uvB), "v"(pxB), "v"(psB));  // keep B live
        subslot(tau + 1, gb, t, bl, jc, wlane, wb0, wb1, rbase, rx, wreg,
                pre, hs, hx, slab, pf0, pf1, pvn, uvB, pxB, psB);
        asm volatile("" :: "v"(uvA), "v"(pxA), "v"(psA));  // keep A live
    }
    if (gb == 0 && t == 0) {
        int one = 1;
        asm volatile("global_store_dword %0, %1, off sc0 sc1"
                     :: "v"(&flags[0]), "v"(one) : "memory");
    }
}

// ---------------- fused residual + LayerNorm ------------------------------
__global__ __launch_bounds__(256) void fused_ln(
    const float* __restrict__ x,
    const __bf16* __restrict__ attn,
    const float* __restrict__ gam,
    const float* __restrict__ bet,
    float* __restrict__ out)
{
    const int row = blockIdx.x;
    const int t = threadIdx.x;
    const size_t base = (size_t)row * DH + t * 4;
    float4 xv = *(const float4*)(x + base);
    bf16x4 av = *(const bf16x4*)(attn + base);
    float v0 = xv.x + (float)av[0];
    float v1 = xv.y + (float)av[1];
    float v2 = xv.z + (float)av[2];
    float v3 = xv.w + (float)av[3];
    float s1 = v0 + v1 + v2 + v3;
    float s2 = v0 * v0 + v1 * v1 + v2 * v2 + v3 * v3;
#pragma unroll
    for (int off = 32; off > 0; off >>= 1) {
        s1 += __shfl_xor(s1, off);
        s2 += __shfl_xor(s2, off);
    }
    __shared__ float red[8];
    const int w = t >> 6, l = t & 63;
    if (l == 0) { red[w] = s1; red[4 + w] = s2; }
    __syncthreads();
    float S1 = red[0] + red[1] + red[2] + red[3];
    float S2 = red[4] + red[5] + red[6] + red[7];
    const float mu = S1 * (1.0f / 1024.0f);
    const float var = S2 * (1.0f / 1024.0f) - mu * mu;
    const float rs = rsqrtf(var + 1e-5f);
    const int c = t * 4;
    float4 gv = *(const float4*)(gam + c);
    float4 bv = *(const float4*)(bet + c);
    float4 o;
    o.x = (v0 - mu) * rs * gv.x + bv.x;
    o.y = (v1 - mu) * rs * gv.y + bv.y;
    o.z = (v2 - mu) * rs * gv.z + bv.z;
    o.w = (v3 - mu) * rs * gv.w + bv.w;
    *(float4*)(out + base) = o;
}

// ---------------- launcher -------------------------------------------------
extern "C" void kernel_launch(void* const* d_in, const int* in_sizes, int n_in,
                              void* d_out, int out_size, void* d_ws, size_t ws_size,
                              hipStream_t stream)
{
    const float* x    = (const float*)d_in[0];
    const float* Wih  = (const float*)d_in[1];
    const float* Whh  = (const float*)d_in[2];
    const float* bih  = (const float*)d_in[3];
    const float* bhh  = (const float*)d_in[4];
    const float* Wout = (const float*)d_in[5];
    const float* lng  = (const float*)d_in[6];
    const float* lnb  = (const float*)d_in[7];
    float* out = (float*)d_out;

    char* ws = (char*)d_ws;
    const size_t BIG = (size_t)MTOT * DH * sizeof(__bf16);  // 134217728
    __bf16* buf0   = (__bf16*)ws;                  // x_bf16, later reused for attn
    __bf16* pre    = (__bf16*)(ws + BIG);
    __bf16* hsbuf  = (__bf16*)(ws + 2 * BIG);
    __bf16* Wih_b  = (__bf16*)(ws + 3 * BIG);
    __bf16* Whh_b  = Wih_b + (size_t)DH * DH;
    __bf16* Wout_b = Whh_b + (size_t)DH * DH;
    float*  bias   = (float*)(Wout_b + (size_t)DH * DH);
    int*    flags  = (int*)(bias + DH);
    __bf16* hx     = (__bf16*)(ws + 3 * BIG + 8 * 1024 * 1024);  // 128KB, 8 slots

    prep_kernel<<<1024, 256, 0, stream>>>(Wih, Whh, Wout, bih, bhh,
                                          Wih_b, Whh_b, Wout_b, bias, flags);
    cvt_bf16_x<<<32768, 256, 0, stream>>>(x, buf0);
    // clear hx: tag bits 00 never match a valid epoch (kills poison + stale replays)
    hipMemsetAsync(hx, 0, 8 * 8 * DH * sizeof(__bf16), stream);
    gemm_bt<<<4096, 256, 0, stream>>>(buf0, Wih_b, bias, pre, MTOT, DH, DH);
    rnn_scan<<<NWORK + NFILL, 512, 0, stream>>>(Whh_b, pre, hsbuf, hx, flags);
    gemm_bt<<<4096, 256, 0, stream>>>(hsbuf, Wout_b, nullptr, buf0, MTOT, DH, DH);
    fused_ln<<<65536, 256, 0, stream>>>(x, buf0, lng, lnb, out);
}

// Round 12
// 12505.389 us; speedup vs baseline: 1.0430x; 1.0430x over previous
//
#include <hip/hip_runtime.h>
#include <hip/hip_bf16.h>

typedef __bf16 bf16x8 __attribute__((ext_vector_type(8)));
typedef __bf16 bf16x4 __attribute__((ext_vector_type(4)));
typedef float  f32x4  __attribute__((ext_vector_type(4)));
typedef unsigned int u32x2 __attribute__((ext_vector_type(2)));
typedef unsigned int u32x4 __attribute__((ext_vector_type(4)));

#define NSTEP 2048
#define NB    32     // batch
#define DH    1024   // hidden = d_model = d_res
#define MTOT  (NSTEP * NB)   // 65536
#define NWORK 8      // worker WGs in rnn_scan
#define NFILL 248    // clock-pinning filler WGs (8+248=256 CUs)
#define FILLER_CAP 60000

__device__ __forceinline__ f32x4 mfma16(bf16x8 a, bf16x8 b, f32x4 c) {
    return __builtin_amdgcn_mfma_f32_16x16x32_bf16(a, b, c, 0, 0, 0);
}

__device__ __forceinline__ void load_lds16(const __bf16* g, void* l) {
    __builtin_amdgcn_global_load_lds(
        (const __attribute__((address_space(1))) void*)g,
        (__attribute__((address_space(3))) void*)l, 16, 0, 0);
}

__device__ __forceinline__ float tanh_fast(float x) {
    float e = exp2f(x * 2.8853900817779268f);
    return 1.0f - 2.0f * __builtin_amdgcn_rcpf(e + 1.0f);
}

// ---------------- prep: convert weights to bf16, sum biases, zero flags ----
__global__ __launch_bounds__(256) void prep_kernel(
    const float* __restrict__ Wih, const float* __restrict__ Whh,
    const float* __restrict__ Wout, const float* __restrict__ bih,
    const float* __restrict__ bhh,
    __bf16* __restrict__ Wih_b, __bf16* __restrict__ Whh_b,
    __bf16* __restrict__ Wout_b, float* __restrict__ bias,
    int* __restrict__ flags)
{
    const int i = blockIdx.x * 256 + threadIdx.x;   // 0..262143
    const size_t off = (size_t)i * 4;
    {
        float4 a = *(const float4*)(Wih + off);
        bf16x4 o = {(__bf16)a.x, (__bf16)a.y, (__bf16)a.z, (__bf16)a.w};
        *(bf16x4*)(Wih_b + off) = o;
    }
    {
        float4 a = *(const float4*)(Whh + off);
        bf16x4 o = {(__bf16)a.x, (__bf16)a.y, (__bf16)a.z, (__bf16)a.w};
        *(bf16x4*)(Whh_b + off) = o;
    }
    {
        float4 a = *(const float4*)(Wout + off);
        bf16x4 o = {(__bf16)a.x, (__bf16)a.y, (__bf16)a.z, (__bf16)a.w};
        *(bf16x4*)(Wout_b + off) = o;
    }
    if (i < DH) bias[i] = bih[i] + bhh[i];
    if (i < 64) {
        int z = 0;
        asm volatile("global_store_dword %0, %1, off sc0 sc1"
                     :: "v"(&flags[i]), "v"(z) : "memory");
    }
}

// ---------------- x fp32 -> bf16 -----------------------------------------
__global__ __launch_bounds__(256) void cvt_bf16_x(
    const float* __restrict__ in, __bf16* __restrict__ outb)
{
    const size_t i = ((size_t)blockIdx.x * 256 + threadIdx.x) * 8;
    float4 a = *(const float4*)(in + i);
    float4 b = *(const float4*)(in + i + 4);
    bf16x8 o = { (__bf16)a.x, (__bf16)a.y, (__bf16)a.z, (__bf16)a.w,
                 (__bf16)b.x, (__bf16)b.y, (__bf16)b.z, (__bf16)b.w };
    *(bf16x8*)(outb + i) = o;
}

// ---------------- bf16 GEMM, C = A(MxK) * B(NxK)^T (+bias), bf16 out ------
__global__ __launch_bounds__(256) void gemm_bt(
    const __bf16* __restrict__ A,
    const __bf16* __restrict__ B,
    const float*  __restrict__ bias,
    __bf16* __restrict__ C,
    int M, int N, int K)
{
    __shared__ __bf16 sA[128 * 64];
    __shared__ __bf16 sB[128 * 64];
    const int nTn = N >> 7;
    const int tm = (int)(blockIdx.x / nTn) << 7;
    const int tn = (int)(blockIdx.x % nTn) << 7;
    const int t = threadIdx.x;
    const int w = t >> 6, l = t & 63;
    const int wy = w & 1, wx = w >> 1;
    const int l16 = l & 15, lhi = l >> 4;
    const int rw = t >> 3;
    const int kc = (t & 7) << 3;

    const __bf16* ga = A + (size_t)(tm + rw) * K + kc;
    const __bf16* gb = B + (size_t)(tn + rw) * K + kc;
    char* lA = (char*)sA + (w * 8) * 128;
    char* lB = (char*)sB + (w * 8) * 128;

    f32x4 acc[4][4] = {};

    for (int k0 = 0; k0 < K; k0 += 64) {
#pragma unroll
        for (int i = 0; i < 4; ++i) {
            load_lds16(ga + (size_t)(i * 32) * K + k0, lA + i * 32 * 128);
            load_lds16(gb + (size_t)(i * 32) * K + k0, lB + i * 32 * 128);
        }
        asm volatile("s_waitcnt vmcnt(0)" ::: "memory");
        __syncthreads();
#pragma unroll
        for (int kk = 0; kk < 2; ++kk) {
            bf16x8 af[4], bfr[4];
#pragma unroll
            for (int i = 0; i < 4; ++i) {
                af[i]  = *(const bf16x8*)(sA + (wy * 64 + i * 16 + l16) * 64 + kk * 32 + lhi * 8);
                bfr[i] = *(const bf16x8*)(sB + (wx * 64 + i * 16 + l16) * 64 + kk * 32 + lhi * 8);
            }
#pragma unroll
            for (int i = 0; i < 4; ++i)
#pragma unroll
                for (int j = 0; j < 4; ++j)
                    acc[i][j] = mfma16(af[i], bfr[j], acc[i][j]);
        }
        __syncthreads();
    }
#pragma unroll
    for (int j = 0; j < 4; ++j) {
        const int col = tn + wx * 64 + j * 16 + l16;
        const float bv = bias ? bias[col] : 0.0f;
#pragma unroll
        for (int i = 0; i < 4; ++i) {
            __bf16* cp = C + (size_t)(tm + wy * 64 + i * 16 + lhi * 4) * N + col;
#pragma unroll
            for (int r = 0; r < 4; ++r)
                cp[(size_t)r * N] = (__bf16)(acc[i][j][r] + bv);
        }
    }
}

// ---------------- persistent RNN scan: LDS-staged, 8 WGs ------------------
// R12 = R10 structure with HALF the WGs: 8 WGs x 8 waves; WG g owns j-cols
// [g*128,(g+1)*128); wave = 16 j x ALL 32 b (two accumulator halves sharing
// the wave's 128-VGPR W-slice). Halves uncached poll traffic (1MB -> 512KB
// per step) and producer-wave count (128 -> 64, smaller skew tail) — the
// last non-latency term in T_round. Everything else identical to R10:
// tag-in-data epoch (flips every 2 steps = hx slot reuse distance), 128KB
// MALL-hot hx ping-pong, plain hs store for the GEMM, per-step LDS staging
// (retry-load IS the poll), fillers pin SCLK.
#define LDU(d, p) asm volatile("global_load_dwordx4 %0, %1, off sc0 sc1" \
                               : "=v"(d) : "v"(p) : "memory");

__global__ __launch_bounds__(512, 1) void rnn_scan(
    const __bf16* __restrict__ Whh,   // [1024][1024] bf16 (row j, col k)
    const __bf16* __restrict__ pre,   // [2048][32][1024] bf16
    __bf16* __restrict__ hs,          // [2048][32][1024] bf16 (plain, for GEMM)
    __bf16* __restrict__ hx,          // [2][32][1024] bf16 ping-pong exchange
    int* __restrict__ flags)          // [0] = done flag
{
    const int gb = blockIdx.x;
    if (gb >= NWORK) {
        // ---- clock-pinning filler ----
        float a = (float)(threadIdx.x + gb) * 1.0e-6f + 1.0f;
        const float m = 1.000001f, d = 0.999999f;
        const int* dp = flags;
        for (int it = 0; it < FILLER_CAP; ++it) {
#pragma unroll
            for (int u = 0; u < 128; ++u) {
                a = __builtin_fmaf(a, m, 1.0e-12f);
                a = __builtin_fmaf(a, d, -1.0e-12f);
            }
            if ((it & 15) == 0) {
                int dn;
                asm volatile("global_load_dword %0, %1, off sc0 sc1\n\t"
                             "s_waitcnt vmcnt(0)"
                             : "=v"(dn) : "v"(dp) : "memory");
                if (dn != 0) break;
            }
        }
        asm volatile("" :: "v"(a));
        return;
    }

    __shared__ char slab[2][65536];    // double-buffered h slab [32 b][1024 j]
    const int t = threadIdx.x;         // 0..511
    const int w = t >> 6;              // 0..7
    const int l = t & 63;
    const int j0 = gb * 128 + w * 16;  // wave's 16 output cols (W rows)
    const int l16 = l & 15;
    const int lhi = l >> 4;
    const int bA = l16;                // batch rows this lane handles
    const int bB = 16 + l16;
    const int jc = j0 + lhi * 4;       // 4 output cols this lane stores

    // A-operand (W rows j0..j0+15): wreg[c] covers k in [c*32, c*32+32)
    bf16x8 wreg[32];
    {
        const __bf16* wb = Whh + (size_t)(j0 + l16) * DH + lhi * 8;
#pragma unroll
        for (int c = 0; c < 32; ++c)
            wreg[c] = *(const bf16x8*)(wb + c * 32);
    }

    // LDS read geometry: row=b, swizzle by b&7 (bA&7 == bB&7)
    const unsigned rbA = (unsigned)bA * 2048 + (unsigned)lhi * 16;
    const unsigned rbB = (unsigned)bB * 2048 + (unsigned)lhi * 16;
    const unsigned rx = (unsigned)((bA & 7) << 4);

    for (int s = 0; s < NSTEP; ++s) {
        bf16x4 pvA = *(const bf16x4*)(pre + ((size_t)s * NB + bA) * DH + jc);
        bf16x4 pvB = *(const bf16x4*)(pre + ((size_t)s * NB + bB) * DH + jc);

        f32x4 aA0 = {0.f, 0.f, 0.f, 0.f}, aA1 = aA0, aA2 = aA0, aA3 = aA0;
        f32x4 aB0 = aA0, aB1 = aA0, aB2 = aA0, aB3 = aA0;
        int bi = 0;

        if (s > 0) {
            const int sl = s - 1;
            bi = sl & 1;
            const unsigned rep = (unsigned)(((sl >> 1) & 1) + 1) * 0x00010001u;
            const char* sp = (const char*)hx + ((size_t)(sl & 1) << 16) + (size_t)t * 16;
            const char* p0 = sp;
            const char* p1 = sp + 8192;
            const char* p2 = sp + 16384;
            const char* p3 = sp + 24576;
            const char* p4 = sp + 32768;
            const char* p5 = sp + 40960;
            const char* p6 = sp + 49152;
            const char* p7 = sp + 57344;
            u32x4 st[8];
            for (;;) {
                LDU(st[0], p0) LDU(st[1], p1) LDU(st[2], p2) LDU(st[3], p3)
                LDU(st[4], p4) LDU(st[5], p5) LDU(st[6], p6) LDU(st[7], p7)
                asm volatile("s_waitcnt vmcnt(0)" ::: "memory");
                __builtin_amdgcn_sched_barrier(0);
                unsigned bad = 0;
#pragma unroll
                for (int i = 0; i < 8; ++i)
                    bad |= (st[i][0] ^ rep) | (st[i][1] ^ rep)
                         | (st[i][2] ^ rep) | (st[i][3] ^ rep);
                if (__all((bad & 0x00030003u) == 0u)) break;
            }
            __builtin_amdgcn_sched_barrier(0);
            // ds_write slice (XOR-swizzled: row stride 2048B would 16-way conflict)
#pragma unroll
            for (int i = 0; i < 8; ++i) {
                unsigned byte = (unsigned)t * 16 + (unsigned)i * 8192;
                unsigned row = byte >> 11;
                unsigned swz = byte ^ ((row & 7) << 4);
                *(u32x4*)(&slab[bi][swz]) = st[i];
            }
            __syncthreads();
            // consume: both batch halves, full k, from LDS
#pragma unroll
            for (int c = 0; c < 32; c += 4) {
                bf16x8 hA0 = *(const bf16x8*)(&slab[bi][(rbA + (unsigned)(c + 0) * 64) ^ rx]);
                bf16x8 hA1 = *(const bf16x8*)(&slab[bi][(rbA + (unsigned)(c + 1) * 64) ^ rx]);
                bf16x8 hA2 = *(const bf16x8*)(&slab[bi][(rbA + (unsigned)(c + 2) * 64) ^ rx]);
                bf16x8 hA3 = *(const bf16x8*)(&slab[bi][(rbA + (unsigned)(c + 3) * 64) ^ rx]);
                aA0 = mfma16(wreg[c + 0], hA0, aA0);
                aA1 = mfma16(wreg[c + 1], hA1, aA1);
                aA2 = mfma16(wreg[c + 2], hA2, aA2);
                aA3 = mfma16(wreg[c + 3], hA3, aA3);
                bf16x8 hB0 = *(const bf16x8*)(&slab[bi][(rbB + (unsigned)(c + 0) * 64) ^ rx]);
                bf16x8 hB1 = *(const bf16x8*)(&slab[bi][(rbB + (unsigned)(c + 1) * 64) ^ rx]);
                bf16x8 hB2 = *(const bf16x8*)(&slab[bi][(rbB + (unsigned)(c + 2) * 64) ^ rx]);
                bf16x8 hB3 = *(const bf16x8*)(&slab[bi][(rbB + (unsigned)(c + 3) * 64) ^ rx]);
                aB0 = mfma16(wreg[c + 0], hB0, aB0);
                aB1 = mfma16(wreg[c + 1], hB1, aB1);
                aB2 = mfma16(wreg[c + 2], hB2, aB2);
                aB3 = mfma16(wreg[c + 3], hB3, aB3);
            }
        }
        f32x4 asA = (aA0 + aA1) + (aA2 + aA3);
        f32x4 asB = (aB0 + aB1) + (aB2 + aB3);

        const unsigned tag = (unsigned)(((s >> 1) & 1) + 1);
        u32x2 uvA, uvB;
        {
            float h0 = tanh_fast(asA[0] + (float)pvA[0]);
            float h1 = tanh_fast(asA[1] + (float)pvA[1]);
            float h2 = tanh_fast(asA[2] + (float)pvA[2]);
            float h3 = tanh_fast(asA[3] + (float)pvA[3]);
            unsigned u0 = (unsigned)__builtin_bit_cast(unsigned short, (__bf16)h0);
            unsigned u1 = (unsigned)__builtin_bit_cast(unsigned short, (__bf16)h1);
            unsigned u2 = (unsigned)__builtin_bit_cast(unsigned short, (__bf16)h2);
            unsigned u3 = (unsigned)__builtin_bit_cast(unsigned short, (__bf16)h3);
            u0 = ((u0 + 2u) & 0xFFFCu) | tag;
            u1 = ((u1 + 2u) & 0xFFFCu) | tag;
            u2 = ((u2 + 2u) & 0xFFFCu) | tag;
            u3 = ((u3 + 2u) & 0xFFFCu) | tag;
            uvA[0] = u0 | (u1 << 16);
            uvA[1] = u2 | (u3 << 16);
        }
        {
            float h0 = tanh_fast(asB[0] + (float)pvB[0]);
            float h1 = tanh_fast(asB[1] + (float)pvB[1]);
            float h2 = tanh_fast(asB[2] + (float)pvB[2]);
            float h3 = tanh_fast(asB[3] + (float)pvB[3]);
            unsigned u0 = (unsigned)__builtin_bit_cast(unsigned short, (__bf16)h0);
            unsigned u1 = (unsigned)__builtin_bit_cast(unsigned short, (__bf16)h1);
            unsigned u2 = (unsigned)__builtin_bit_cast(unsigned short, (__bf16)h2);
            unsigned u3 = (unsigned)__builtin_bit_cast(unsigned short, (__bf16)h3);
            u0 = ((u0 + 2u) & 0xFFFCu) | tag;
            u1 = ((u1 + 2u) & 0xFFFCu) | tag;
            u2 = ((u2 + 2u) & 0xFFFCu) | tag;
            u3 = ((u3 + 2u) & 0xFFFCu) | tag;
            uvB[0] = u0 | (u1 << 16);
            uvB[1] = u2 | (u3 << 16);
        }
        __bf16* oxA = hx + ((size_t)(s & 1) * NB + bA) * DH + jc;
        __bf16* oxB = hx + ((size_t)(s & 1) * NB + bB) * DH + jc;
        asm volatile("global_store_dwordx2 %0, %1, off sc0 sc1"
                     :: "v"(oxA), "v"(uvA) : "memory");
        asm volatile("global_store_dwordx2 %0, %1, off sc0 sc1"
                     :: "v"(oxB), "v"(uvB) : "memory");
        *(u32x2*)(hs + ((size_t)s * NB + bA) * DH + jc) = uvA;
        *(u32x2*)(hs + ((size_t)s * NB + bB) * DH + jc) = uvB;
        // no drain, no flags: consumers validate the data itself
    }
    if (gb == 0 && t == 0) {
        int one = 1;
        asm volatile("global_store_dword %0, %1, off sc0 sc1"
                     :: "v"(&flags[0]), "v"(one) : "memory");
    }
}

// ---------------- fused residual + LayerNorm ------------------------------
__global__ __launch_bounds__(256) void fused_ln(
    const float* __restrict__ x,
    const __bf16* __restrict__ attn,
    const float* __restrict__ gam,
    const float* __restrict__ bet,
    float* __restrict__ out)
{
    const int row = blockIdx.x;
    const int t = threadIdx.x;
    const size_t base = (size_t)row * DH + t * 4;
    float4 xv = *(const float4*)(x + base);
    bf16x4 av = *(const bf16x4*)(attn + base);
    float v0 = xv.x + (float)av[0];
    float v1 = xv.y + (float)av[1];
    float v2 = xv.z + (float)av[2];
    float v3 = xv.w + (float)av[3];
    float s1 = v0 + v1 + v2 + v3;
    float s2 = v0 * v0 + v1 * v1 + v2 * v2 + v3 * v3;
#pragma unroll
    for (int off = 32; off > 0; off >>= 1) {
        s1 += __shfl_xor(s1, off);
        s2 += __shfl_xor(s2, off);
    }
    __shared__ float red[8];
    const int w = t >> 6, l = t & 63;
    if (l == 0) { red[w] = s1; red[4 + w] = s2; }
    __syncthreads();
    float S1 = red[0] + red[1] + red[2] + red[3];
    float S2 = red[4] + red[5] + red[6] + red[7];
    const float mu = S1 * (1.0f / 1024.0f);
    const float var = S2 * (1.0f / 1024.0f) - mu * mu;
    const float rs = rsqrtf(var + 1e-5f);
    const int c = t * 4;
    float4 gv = *(const float4*)(gam + c);
    float4 bv = *(const float4*)(bet + c);
    float4 o;
    o.x = (v0 - mu) * rs * gv.x + bv.x;
    o.y = (v1 - mu) * rs * gv.y + bv.y;
    o.z = (v2 - mu) * rs * gv.z + bv.z;
    o.w = (v3 - mu) * rs * gv.w + bv.w;
    *(float4*)(out + base) = o;
}

// ---------------- launcher -------------------------------------------------
extern "C" void kernel_launch(void* const* d_in, const int* in_sizes, int n_in,
                              void* d_out, int out_size, void* d_ws, size_t ws_size,
                              hipStream_t stream)
{
    const float* x    = (const float*)d_in[0];
    const float* Wih  = (const float*)d_in[1];
    const float* Whh  = (const float*)d_in[2];
    const float* bih  = (const float*)d_in[3];
    const float* bhh  = (const float*)d_in[4];
    const float* Wout = (const float*)d_in[5];
    const float* lng  = (const float*)d_in[6];
    const float* lnb  = (const float*)d_in[7];
    float* out = (float*)d_out;

    char* ws = (char*)d_ws;
    const size_t BIG = (size_t)MTOT * DH * sizeof(__bf16);  // 134217728
    __bf16* buf0   = (__bf16*)ws;                  // x_bf16, later reused for attn
    __bf16* pre    = (__bf16*)(ws + BIG);
    __bf16* hsbuf  = (__bf16*)(ws + 2 * BIG);
    __bf16* Wih_b  = (__bf16*)(ws + 3 * BIG);
    __bf16* Whh_b  = Wih_b + (size_t)DH * DH;
    __bf16* Wout_b = Whh_b + (size_t)DH * DH;
    float*  bias   = (float*)(Wout_b + (size_t)DH * DH);
    int*    flags  = (int*)(bias + DH);
    __bf16* hx     = (__bf16*)(ws + 3 * BIG + 8 * 1024 * 1024);  // 128KB ping-pong

    prep_kernel<<<1024, 256, 0, stream>>>(Wih, Whh, Wout, bih, bhh,
                                          Wih_b, Whh_b, Wout_b, bias, flags);
    cvt_bf16_x<<<32768, 256, 0, stream>>>(x, buf0);
    // clear hx: tag bits 00 never match a valid epoch (kills poison + stale replays)
    hipMemsetAsync(hx, 0, 2 * NB * DH * sizeof(__bf16), stream);
    gemm_bt<<<4096, 256, 0, stream>>>(buf0, Wih_b, bias, pre, MTOT, DH, DH);
    rnn_scan<<<NWORK + NFILL, 512, 0, stream>>>(Whh_b, pre, hsbuf, hx, flags);
    gemm_bt<<<4096, 256, 0, stream>>>(hsbuf, Wout_b, nullptr, buf0, MTOT, DH, DH);
    fused_ln<<<65536, 256, 0, stream>>>(x, buf0, lng, lnb, out);
}

// Round 13
// 8390.504 us; speedup vs baseline: 1.5546x; 1.4904x over previous
//
#include <hip/hip_runtime.h>
#include <hip/hip_bf16.h>

typedef __bf16 bf16x8 __attribute__((ext_vector_type(8)));
typedef __bf16 bf16x4 __attribute__((ext_vector_type(4)));
typedef float  f32x4  __attribute__((ext_vector_type(4)));
typedef unsigned int u32x2 __attribute__((ext_vector_type(2)));
typedef unsigned int u32x4 __attribute__((ext_vector_type(4)));

#define NSTEP 2048
#define NB    32     // batch
#define DH    1024   // hidden = d_model = d_res
#define MTOT  (NSTEP * NB)   // 65536
#define NWORK 16     // worker WGs in rnn_scan
#define NFILL 208    // clock-pinning filler WGs (16+208=224 < 256 CUs -> all resident)
#define FILLER_CAP 60000

__device__ __forceinline__ f32x4 mfma16(bf16x8 a, bf16x8 b, f32x4 c) {
    return __builtin_amdgcn_mfma_f32_16x16x32_bf16(a, b, c, 0, 0, 0);
}

__device__ __forceinline__ void load_lds16(const __bf16* g, void* l) {
    __builtin_amdgcn_global_load_lds(
        (const __attribute__((address_space(1))) void*)g,
        (__attribute__((address_space(3))) void*)l, 16, 0, 0);
}

__device__ __forceinline__ float tanh_fast(float x) {
    float e = exp2f(x * 2.8853900817779268f);
    return 1.0f - 2.0f * __builtin_amdgcn_rcpf(e + 1.0f);
}

// ---------------- prep: convert weights to bf16, sum biases, zero flags ----
__global__ __launch_bounds__(256) void prep_kernel(
    const float* __restrict__ Wih, const float* __restrict__ Whh,
    const float* __restrict__ Wout, const float* __restrict__ bih,
    const float* __restrict__ bhh,
    __bf16* __restrict__ Wih_b, __bf16* __restrict__ Whh_b,
    __bf16* __restrict__ Wout_b, float* __restrict__ bias,
    int* __restrict__ flags)
{
    const int i = blockIdx.x * 256 + threadIdx.x;   // 0..262143
    const size_t off = (size_t)i * 4;
    {
        float4 a = *(const float4*)(Wih + off);
        bf16x4 o = {(__bf16)a.x, (__bf16)a.y, (__bf16)a.z, (__bf16)a.w};
        *(bf16x4*)(Wih_b + off) = o;
    }
    {
        float4 a = *(const float4*)(Whh + off);
        bf16x4 o = {(__bf16)a.x, (__bf16)a.y, (__bf16)a.z, (__bf16)a.w};
        *(bf16x4*)(Whh_b + off) = o;
    }
    {
        float4 a = *(const float4*)(Wout + off);
        bf16x4 o = {(__bf16)a.x, (__bf16)a.y, (__bf16)a.z, (__bf16)a.w};
        *(bf16x4*)(Wout_b + off) = o;
    }
    if (i < DH) bias[i] = bih[i] + bhh[i];
    if (i < 64) {
        int z = 0;
        asm volatile("global_store_dword %0, %1, off sc0 sc1"
                     :: "v"(&flags[i]), "v"(z) : "memory");
    }
}

// ---------------- x fp32 -> bf16 -----------------------------------------
__global__ __launch_bounds__(256) void cvt_bf16_x(
    const float* __restrict__ in, __bf16* __restrict__ outb)
{
    const size_t i = ((size_t)blockIdx.x * 256 + threadIdx.x) * 8;
    float4 a = *(const float4*)(in + i);
    float4 b = *(const float4*)(in + i + 4);
    bf16x8 o = { (__bf16)a.x, (__bf16)a.y, (__bf16)a.z, (__bf16)a.w,
                 (__bf16)b.x, (__bf16)b.y, (__bf16)b.z, (__bf16)b.w };
    *(bf16x8*)(outb + i) = o;
}

// ---------------- bf16 GEMM, C = A(MxK) * B(NxK)^T (+bias), bf16 out ------
__global__ __launch_bounds__(256) void gemm_bt(
    const __bf16* __restrict__ A,
    const __bf16* __restrict__ B,
    const float*  __restrict__ bias,
    __bf16* __restrict__ C,
    int M, int N, int K)
{
    __shared__ __bf16 sA[128 * 64];
    __shared__ __bf16 sB[128 * 64];
    const int nTn = N >> 7;
    const int tm = (int)(blockIdx.x / nTn) << 7;
    const int tn = (int)(blockIdx.x % nTn) << 7;
    const int t = threadIdx.x;
    const int w = t >> 6, l = t & 63;
    const int wy = w & 1, wx = w >> 1;
    const int l16 = l & 15, lhi = l >> 4;
    const int rw = t >> 3;
    const int kc = (t & 7) << 3;

    const __bf16* ga = A + (size_t)(tm + rw) * K + kc;
    const __bf16* gb = B + (size_t)(tn + rw) * K + kc;
    char* lA = (char*)sA + (w * 8) * 128;
    char* lB = (char*)sB + (w * 8) * 128;

    f32x4 acc[4][4] = {};

    for (int k0 = 0; k0 < K; k0 += 64) {
#pragma unroll
        for (int i = 0; i < 4; ++i) {
            load_lds16(ga + (size_t)(i * 32) * K + k0, lA + i * 32 * 128);
            load_lds16(gb + (size_t)(i * 32) * K + k0, lB + i * 32 * 128);
        }
        asm volatile("s_waitcnt vmcnt(0)" ::: "memory");
        __syncthreads();
#pragma unroll
        for (int kk = 0; kk < 2; ++kk) {
            bf16x8 af[4], bfr[4];
#pragma unroll
            for (int i = 0; i < 4; ++i) {
                af[i]  = *(const bf16x8*)(sA + (wy * 64 + i * 16 + l16) * 64 + kk * 32 + lhi * 8);
                bfr[i] = *(const bf16x8*)(sB + (wx * 64 + i * 16 + l16) * 64 + kk * 32 + lhi * 8);
            }
#pragma unroll
            for (int i = 0; i < 4; ++i)
#pragma unroll
                for (int j = 0; j < 4; ++j)
                    acc[i][j] = mfma16(af[i], bfr[j], acc[i][j]);
        }
        __syncthreads();
    }
#pragma unroll
    for (int j = 0; j < 4; ++j) {
        const int col = tn + wx * 64 + j * 16 + l16;
        const float bv = bias ? bias[col] : 0.0f;
#pragma unroll
        for (int i = 0; i < 4; ++i) {
            __bf16* cp = C + (size_t)(tm + wy * 64 + i * 16 + lhi * 4) * N + col;
#pragma unroll
            for (int r = 0; r < 4; ++r)
                cp[(size_t)r * N] = (__bf16)(acc[i][j][r] + bv);
        }
    }
}

// ---------------- persistent RNN scan: LDS-staged, MALL-hot exchange ------
// (R10 optimum, restored byte-for-byte.) 16 worker WGs x 8 waves. WG g owns
// j-cols [g*64,(g+1)*64). Swapped MFMA: D[j][b]; lane produces 4
// j-consecutive bf16 = one dwordx2. Exchange via 128KB MALL-hot ping-pong
// hx[2][32][1024] with tag-in-data (2-bit epoch, flips every 2 steps = slot
// reuse distance); hs output written with plain cached stores (kernel
// boundary publishes to the GEMM). Per step the WG stages the 64KB slab
// once into LDS (retry-load IS the poll), one barrier, 8 waves consume.
// Fillers pin SCLK on remaining CUs.
#define LDU(d, p) asm volatile("global_load_dwordx4 %0, %1, off sc0 sc1" \
                               : "=v"(d) : "v"(p) : "memory");

__global__ __launch_bounds__(512, 2) void rnn_scan(
    const __bf16* __restrict__ Whh,   // [1024][1024] bf16 (row j, col k)
    const __bf16* __restrict__ pre,   // [2048][32][1024] bf16
    __bf16* __restrict__ hs,          // [2048][32][1024] bf16 (plain, for GEMM)
    __bf16* __restrict__ hx,          // [2][32][1024] bf16 ping-pong exchange
    int* __restrict__ flags)          // [0] = done flag
{
    const int gb = blockIdx.x;
    if (gb >= NWORK) {
        // ---- clock-pinning filler ----
        float a = (float)(threadIdx.x + gb) * 1.0e-6f + 1.0f;
        const float m = 1.000001f, d = 0.999999f;
        const int* dp = flags;
        for (int it = 0; it < FILLER_CAP; ++it) {
#pragma unroll
            for (int u = 0; u < 128; ++u) {
                a = __builtin_fmaf(a, m, 1.0e-12f);
                a = __builtin_fmaf(a, d, -1.0e-12f);
            }
            if ((it & 15) == 0) {
                int dn;
                asm volatile("global_load_dword %0, %1, off sc0 sc1\n\t"
                             "s_waitcnt vmcnt(0)"
                             : "=v"(dn) : "v"(dp) : "memory");
                if (dn != 0) break;
            }
        }
        asm volatile("" :: "v"(a));
        return;
    }

    __shared__ char slab[2][65536];    // double-buffered h slab [32 b][1024 j]
    const int t = threadIdx.x;         // 0..511
    const int w = t >> 6;              // 0..7
    const int l = t & 63;
    const int mhalf = w & 1;
    const int jg = w >> 1;             // 0..3
    const int j0 = gb * 64 + jg * 16;  // wave's 16 output cols (W rows)
    const int l16 = l & 15;
    const int lhi = l >> 4;
    const int b  = mhalf * 16 + l16;   // batch row this lane produces/consumes
    const int jc = j0 + lhi * 4;       // 4 output cols this lane stores

    // A-operand (W rows j0..j0+15): wreg[c] covers k in [c*32, c*32+32)
    bf16x8 wreg[32];
    {
        const __bf16* wb = Whh + (size_t)(j0 + l16) * DH + lhi * 8;
#pragma unroll
        for (int c = 0; c < 32; ++c)
            wreg[c] = *(const bf16x8*)(wb + c * 32);
    }

    // LDS read geometry for this lane's B-fragments: row=b, swizzle by b&7
    const unsigned rbase = (unsigned)b * 2048 + (unsigned)lhi * 16;
    const unsigned rx = (unsigned)((b & 7) << 4);

    for (int s = 0; s < NSTEP; ++s) {
        bf16x4 pv = *(const bf16x4*)(pre + ((size_t)s * NB + b) * DH + jc);

        f32x4 acc0 = {0.f, 0.f, 0.f, 0.f}, acc1 = acc0, acc2 = acc0, acc3 = acc0;
        int bi = 0;

        if (s > 0) {
            const int sl = s - 1;
            bi = sl & 1;
            const unsigned rep = (unsigned)(((sl >> 1) & 1) + 1) * 0x00010001u;
            const char* sp = (const char*)hx + ((size_t)(sl & 1) << 16) + (size_t)t * 16;
            const char* p0 = sp;
            const char* p1 = sp + 8192;
            const char* p2 = sp + 16384;
            const char* p3 = sp + 24576;
            const char* p4 = sp + 32768;
            const char* p5 = sp + 40960;
            const char* p6 = sp + 49152;
            const char* p7 = sp + 57344;
            u32x4 st[8];
            for (;;) {
                LDU(st[0], p0) LDU(st[1], p1) LDU(st[2], p2) LDU(st[3], p3)
                LDU(st[4], p4) LDU(st[5], p5) LDU(st[6], p6) LDU(st[7], p7)
                asm volatile("s_waitcnt vmcnt(0)" ::: "memory");
                __builtin_amdgcn_sched_barrier(0);
                unsigned bad = 0;
#pragma unroll
                for (int i = 0; i < 8; ++i)
                    bad |= (st[i][0] ^ rep) | (st[i][1] ^ rep)
                         | (st[i][2] ^ rep) | (st[i][3] ^ rep);
                if (__all((bad & 0x00030003u) == 0u)) break;
            }
            __builtin_amdgcn_sched_barrier(0);
            // ds_write slice (XOR-swizzled: row stride 2048B would 16-way conflict)
#pragma unroll
            for (int i = 0; i < 8; ++i) {
                unsigned byte = (unsigned)t * 16 + (unsigned)i * 8192;
                unsigned row = byte >> 11;
                unsigned swz = byte ^ ((row & 7) << 4);
                *(u32x4*)(&slab[bi][swz]) = st[i];
            }
            __syncthreads();
            // consume: this wave's batch-half rows, full k, from LDS
#pragma unroll
            for (int c = 0; c < 32; c += 4) {
                bf16x8 h0 = *(const bf16x8*)(&slab[bi][(rbase + (unsigned)(c + 0) * 64) ^ rx]);
                bf16x8 h1 = *(const bf16x8*)(&slab[bi][(rbase + (unsigned)(c + 1) * 64) ^ rx]);
                bf16x8 h2 = *(const bf16x8*)(&slab[bi][(rbase + (unsigned)(c + 2) * 64) ^ rx]);
                bf16x8 h3 = *(const bf16x8*)(&slab[bi][(rbase + (unsigned)(c + 3) * 64) ^ rx]);
                acc0 = mfma16(wreg[c + 0], h0, acc0);
                acc1 = mfma16(wreg[c + 1], h1, acc1);
                acc2 = mfma16(wreg[c + 2], h2, acc2);
                acc3 = mfma16(wreg[c + 3], h3, acc3);
            }
        }
        f32x4 accs = (acc0 + acc1) + (acc2 + acc3);

        float h0 = tanh_fast(accs[0] + (float)pv[0]);
        float h1 = tanh_fast(accs[1] + (float)pv[1]);
        float h2 = tanh_fast(accs[2] + (float)pv[2]);
        float h3 = tanh_fast(accs[3] + (float)pv[3]);
        // tag low 2 bits of each bf16 with epoch (round to nearest 4 ulp);
        // epoch flips every 2 steps = slot reuse distance
        const unsigned tag = (unsigned)(((s >> 1) & 1) + 1);
        unsigned u0 = (unsigned)__builtin_bit_cast(unsigned short, (__bf16)h0);
        unsigned u1 = (unsigned)__builtin_bit_cast(unsigned short, (__bf16)h1);
        unsigned u2 = (unsigned)__builtin_bit_cast(unsigned short, (__bf16)h2);
        unsigned u3 = (unsigned)__builtin_bit_cast(unsigned short, (__bf16)h3);
        u0 = ((u0 + 2u) & 0xFFFCu) | tag;
        u1 = ((u1 + 2u) & 0xFFFCu) | tag;
        u2 = ((u2 + 2u) & 0xFFFCu) | tag;
        u3 = ((u3 + 2u) & 0xFFFCu) | tag;
        u32x2 uval;
        uval[0] = u0 | (u1 << 16);
        uval[1] = u2 | (u3 << 16);
        // exchange store: uncached, MALL-hot ping-pong slot
        __bf16* ox = hx + ((size_t)(s & 1) * NB + b) * DH + jc;
        asm volatile("global_store_dwordx2 %0, %1, off sc0 sc1"
                     :: "v"(ox), "v"(uval) : "memory");
        // output store: plain cached (GEMM reads it after kernel boundary)
        *(u32x2*)(hs + ((size_t)s * NB + b) * DH + jc) = uval;
        // no drain, no flags: consumers validate the data itself
    }
    if (gb == 0 && t == 0) {
        int one = 1;
        asm volatile("global_store_dword %0, %1, off sc0 sc1"
                     :: "v"(&flags[0]), "v"(one) : "memory");
    }
}

// ---------------- fused residual + LayerNorm ------------------------------
__global__ __launch_bounds__(256) void fused_ln(
    const float* __restrict__ x,
    const __bf16* __restrict__ attn,
    const float* __restrict__ gam,
    const float* __restrict__ bet,
    float* __restrict__ out)
{
    const int row = blockIdx.x;
    const int t = threadIdx.x;
    const size_t base = (size_t)row * DH + t * 4;
    float4 xv = *(const float4*)(x + base);
    bf16x4 av = *(const bf16x4*)(attn + base);
    float v0 = xv.x + (float)av[0];
    float v1 = xv.y + (float)av[1];
    float v2 = xv.z + (float)av[2];
    float v3 = xv.w + (float)av[3];
    float s1 = v0 + v1 + v2 + v3;
    float s2 = v0 * v0 + v1 * v1 + v2 * v2 + v3 * v3;
#pragma unroll
    for (int off = 32; off > 0; off >>= 1) {
        s1 += __shfl_xor(s1, off);
        s2 += __shfl_xor(s2, off);
    }
    __shared__ float red[8];
    const int w = t >> 6, l = t & 63;
    if (l == 0) { red[w] = s1; red[4 + w] = s2; }
    __syncthreads();
    float S1 = red[0] + red[1] + red[2] + red[3];
    float S2 = red[4] + red[5] + red[6] + red[7];
    const float mu = S1 * (1.0f / 1024.0f);
    const float var = S2 * (1.0f / 1024.0f) - mu * mu;
    const float rs = rsqrtf(var + 1e-5f);
    const int c = t * 4;
    float4 gv = *(const float4*)(gam + c);
    float4 bv = *(const float4*)(bet + c);
    float4 o;
    o.x = (v0 - mu) * rs * gv.x + bv.x;
    o.y = (v1 - mu) * rs * gv.y + bv.y;
    o.z = (v2 - mu) * rs * gv.z + bv.z;
    o.w = (v3 - mu) * rs * gv.w + bv.w;
    *(float4*)(out + base) = o;
}

// ---------------- launcher -------------------------------------------------
extern "C" void kernel_launch(void* const* d_in, const int* in_sizes, int n_in,
                              void* d_out, int out_size, void* d_ws, size_t ws_size,
                              hipStream_t stream)
{
    const float* x    = (const float*)d_in[0];
    const float* Wih  = (const float*)d_in[1];
    const float* Whh  = (const float*)d_in[2];
    const float* bih  = (const float*)d_in[3];
    const float* bhh  = (const float*)d_in[4];
    const float* Wout = (const float*)d_in[5];
    const float* lng  = (const float*)d_in[6];
    const float* lnb  = (const float*)d_in[7];
    float* out = (float*)d_out;

    char* ws = (char*)d_ws;
    const size_t BIG = (size_t)MTOT * DH * sizeof(__bf16);  // 134217728
    __bf16* buf0   = (__bf16*)ws;                  // x_bf16, later reused for attn
    __bf16* pre    = (__bf16*)(ws + BIG);
    __bf16* hsbuf  = (__bf16*)(ws + 2 * BIG);
    __bf16* Wih_b  = (__bf16*)(ws + 3 * BIG);
    __bf16* Whh_b  = Wih_b + (size_t)DH * DH;
    __bf16* Wout_b = Whh_b + (size_t)DH * DH;
    float*  bias   = (float*)(Wout_b + (size_t)DH * DH);
    int*    flags  = (int*)(bias + DH);
    __bf16* hx     = (__bf16*)(ws + 3 * BIG + 8 * 1024 * 1024);  // 128KB ping-pong

    prep_kernel<<<1024, 256, 0, stream>>>(Wih, Whh, Wout, bih, bhh,
                                          Wih_b, Whh_b, Wout_b, bias, flags);
    cvt_bf16_x<<<32768, 256, 0, stream>>>(x, buf0);
    // clear hx: tag bits 00 never match a valid epoch (kills poison + stale replays)
    hipMemsetAsync(hx, 0, 2 * NB * DH * sizeof(__bf16), stream);
    gemm_bt<<<4096, 256, 0, stream>>>(buf0, Wih_b, bias, pre, MTOT, DH, DH);
    rnn_scan<<<NWORK + NFILL, 512, 0, stream>>>(Whh_b, pre, hsbuf, hx, flags);
    gemm_bt<<<4096, 256, 0, stream>>>(hsbuf, Wout_b, nullptr, buf0, MTOT, DH, DH);
    fused_ln<<<65536, 256, 0, stream>>>(x, buf0, lng, lnb, out);
}